// Round 8
// baseline (233.385 us; speedup 1.0000x reference)
//
#include <hip/hip_runtime.h>
#include <math.h>

#define NORB 13
#define NORB2 (NORB * NORB)
#define GB 8                        // b-blocks per strip (8*104B per row)
#define SF (NORB * GB * NORB * 2)   // strip floats = 2704
#define SF4 (SF / 4)                // 676 float4 per strip
#define ROWF4 (GB * NORB * 2 / 4)   // 52 float4 per row

typedef float fx4 __attribute__((ext_vector_type(4)));   // clang-native float4

// block id per orbital index for L_LIST=[0,0,1,1,2] -> sizes 1,1,3,3,5
__device__ __forceinline__ int blk_of(int p) {
    return p < 1 ? 0 : (p < 2 ? 1 : (p < 5 ? 2 : (p < 8 ? 3 : 4)));
}
__device__ __forceinline__ float ffac(int p, int q) {
    int bp = blk_of(p), bq = blk_of(q);
    return bp < bq ? 1.0f : (bp == bq ? 0.5f : 0.0f);
}

// ---- single-WG CSR build over (a, b-group) bins ----------------------------
__global__ void __launch_bounds__(256)
k_build(const int* __restrict__ edge_index, int* __restrict__ rowptr,
        int* __restrict__ entries, int E, int N, int ngroups) {
    extern __shared__ int sm[];            // cnt[nbins] + cursor[nbins] + part[257]
    int nbins = N * ngroups;
    int* cnt    = sm;
    int* cursor = sm + nbins;
    int* part   = sm + 2 * nbins;
    int tid = threadIdx.x;

    for (int i = tid; i < nbins; i += 256) cnt[i] = 0;
    __syncthreads();

    for (int e = tid; e < E; e += 256) {
        int ie = edge_index[e], je = edge_index[E + e];
        atomicAdd(cnt + ie * ngroups + je / GB, 1);
        atomicAdd(cnt + je * ngroups + ie / GB, 1);
    }
    __syncthreads();

    int per = nbins / 256;
    int base = tid * per;
    int s = 0;
    for (int i = 0; i < per; ++i) s += cnt[base + i];
    part[tid + 1] = s;
    __syncthreads();
    if (tid == 0) {
        part[0] = 0;
        for (int i = 1; i <= 256; ++i) part[i] += part[i - 1];
    }
    __syncthreads();
    int run = part[tid];
    for (int i = 0; i < per; ++i) {
        rowptr[base + i] = run;
        cursor[base + i] = run;
        run += cnt[base + i];
    }
    if (tid == 255) rowptr[nbins] = run;
    __syncthreads();

    for (int e = tid; e < E; e += 256) {
        int ie = edge_index[e], je = edge_index[E + e];
        int pos = atomicAdd(cursor + ie * ngroups + je / GB, 1);
        entries[pos] = (e << 9) | je;                   // forward: phase * hopF
        pos = atomicAdd(cursor + je * ngroups + ie / GB, 1);
        entries[pos] = (e << 9) | 256 | ie;             // reverse: conj * hopF^T
    }
}

// ---- fused assemble: one WG per (a, b-group); loops all K ------------------
// Double-buffered LDS strips, ONE barrier per k; stores of strip k drain
// while strip k+1 accumulates (no synchronous vmcnt(0) after the burst).
__global__ void __launch_bounds__(256)
k_assemble(const float* __restrict__ hopping,
           const float* __restrict__ onsite,
           const float* __restrict__ kpoints,
           const float* __restrict__ cell_shift,
           const int* __restrict__ rowptr,
           const int* __restrict__ entries,
           float* __restrict__ out,
           int N, int K, int ld, int es, int ngroups) {
    int g  = blockIdx.x % ngroups;
    int a  = blockIdx.x / ngroups;
    int tid = threadIdx.x;
    int b0 = g * GB;
    int nb = min(GB, N - b0);

    __shared__ __align__(16) float lds[2 * SF];      // 21632 B -> 7 WGs/CU
    fx4* lds4 = (fx4*)lds;
    for (int i = tid; i < 2 * SF4; i += 256)
        lds4[i] = (fx4){0.f, 0.f, 0.f, 0.f};

    int p = 0, q = 0;
    bool act = tid < NORB2;
    if (act) { p = tid / NORB; q = tid - p * NORB; }
    float fpq = act ? ffac(p, q) : 0.f;
    float fqp = act ? ffac(q, p) : 0.f;

    // onsite hermitized value for the diagonal block (k-independent)
    bool diag = (a >= b0 && a < b0 + nb);
    float onv = 0.f;
    int  ondst = 0;
    if (diag && act) {
        const float* on = onsite + (size_t)a * NORB2;
        onv = on[p * NORB + q] * fpq + on[q * NORB + p] * fqp;
        ondst = (p * GB * NORB + (a - b0) * NORB + q) * 2;
    }

    int bin = a * ngroups + g;
    int beg = rowptr[bin], end = rowptr[bin + 1];
    __syncthreads();                                  // zero-init visible

    bool fastpath = (es == 2) && (nb == GB);

    // ---- accumulate strip k into buffer (k&1) ----
    auto accumulate = [&](int k) {
        float* B = lds + (k & 1) * SF;
        float kx = kpoints[3 * k], ky = kpoints[3 * k + 1], kz = kpoints[3 * k + 2];
        if (diag && act) B[ondst] += onv;
        for (int it = beg; it < end; ++it) {
            int ent = entries[it];                    // uniform (L1-hot)
            int e = ent >> 9;
            int rev = ent & 256;
            int i = (ent & 255) - b0;
            float Rx = cell_shift[3 * e], Ry = cell_shift[3 * e + 1], Rz = cell_shift[3 * e + 2];
            float d = kx * Rx + ky * Ry + kz * Rz;
            float s, c;
            __sincosf(-6.2831853071795864f * d, &s, &c);  // exp(-i*2pi*d)=c+i*s
            float im = rev ? -s : s;
            if (act) {
                const float* h = hopping + (size_t)e * NORB2;
                float hv = rev ? h[q * NORB + p] * fqp : h[p * NORB + q] * fpq;
                int base = (p * GB * NORB + i * NORB + q) * 2;
                B[base]     += c * hv;
                B[base + 1] += im * hv;
            }
        }
    };

    // ---- store strip k from buffer (k&1), re-zeroing as we go ----
    auto store_strip = [&](int k) {
        if (fastpath) {
            fx4* B4 = lds4 + (k & 1) * SF4;
            fx4* o4 = (fx4*)out;
            for (int idx = tid; idx < NORB * ROWF4; idx += 256) {
                int row = idx / ROWF4;
                int col = idx - row * ROWF4;
                fx4 v = B4[idx];
                B4[idx] = (fx4){0.f, 0.f, 0.f, 0.f};
                size_t gc = ((size_t)k * ld + (size_t)a * NORB + row) * ld + (size_t)b0 * NORB;
                o4[(gc >> 1) + col] = v;
            }
        } else if (es == 2) {
            float* B = lds + (k & 1) * SF;
            float2* o2 = (float2*)out;
            int nelem = NORB * nb * NORB;
            for (int idx = tid; idx < nelem; idx += 256) {
                int row = idx / (nb * NORB);
                int rem = idx - row * nb * NORB;
                size_t gc = ((size_t)k * ld + (size_t)a * NORB + row) * ld + (size_t)b0 * NORB + rem;
                int li = (row * GB * NORB + rem) * 2;
                o2[gc] = make_float2(B[li], B[li + 1]);
                B[li] = 0.f; B[li + 1] = 0.f;
            }
        } else {
            float* B = lds + (k & 1) * SF;
            int nelem = NORB * nb * NORB;
            for (int idx = tid; idx < nelem; idx += 256) {
                int row = idx / (nb * NORB);
                int rem = idx - row * nb * NORB;
                size_t gc = ((size_t)k * ld + (size_t)a * NORB + row) * ld + (size_t)b0 * NORB + rem;
                int li = (row * GB * NORB + rem) * 2;
                out[gc] = B[li];
                B[li] = 0.f; B[li + 1] = 0.f;
            }
        }
    };

    accumulate(0);
    for (int k = 0; k < K; ++k) {
        __syncthreads();          // acc(k) done; store(k-1) drained; rezero visible
        store_strip(k);           // burst; drains during acc(k+1)
        if (k + 1 < K) accumulate(k + 1);
    }
}

extern "C" void kernel_launch(void* const* d_in, const int* in_sizes, int n_in,
                              void* d_out, int out_size, void* d_ws, size_t ws_size,
                              hipStream_t stream) {
    const float* hopping    = (const float*)d_in[0];
    const float* onsite     = (const float*)d_in[1];
    const float* kpoints    = (const float*)d_in[2];
    const float* cell_shift = (const float*)d_in[3];
    const int*   edge_index = (const int*)d_in[4];
    float* out = (float*)d_out;

    int E = in_sizes[0] / NORB2;   // 2048
    int N = in_sizes[1] / NORB2;   // 128
    int K = in_sizes[2] / 3;       // 16
    int ld = N * NORB;             // 1664
    int ngroups = (N + GB - 1) / GB;   // 16
    int nbins = N * ngroups;           // 2048

    size_t full = (size_t)K * ld * ld * 2;
    int es = ((size_t)out_size >= full) ? 2 : 1;

    // workspace (ints): rowptr[nbins+1], entries[2E]
    int* rowptr  = (int*)d_ws;
    int* entries = rowptr + nbins + 1;

    size_t build_lds = (size_t)(2 * nbins + 257) * sizeof(int);
    k_build<<<1, 256, build_lds, stream>>>(edge_index, rowptr, entries, E, N, ngroups);

    int nwg = N * ngroups;                      // 2048
    k_assemble<<<nwg, 256, 0, stream>>>(hopping, onsite, kpoints, cell_shift,
                                        rowptr, entries, out, N, K, ld, es, ngroups);
}